// Round 2
// baseline (710.714 us; speedup 1.0000x reference)
//
#include <hip/hip_runtime.h>
#include <hip/hip_bf16.h>
#include <math.h>

typedef __hip_bfloat16 bf16;
typedef __attribute__((ext_vector_type(8))) short short8;
typedef __attribute__((ext_vector_type(4))) float f32x4;

static constexpr int kB = 64;
static constexpr int kS = 100;
static constexpr int kD = 1024;
static constexpr int kH = 16;
static constexpr int kF = 4096;
static constexpr int kRows = kB * kS;  // 6400

// ---------------------------------------------------------------- helpers
__device__ __forceinline__ void gload_lds16(const void* g, void* l) {
    __builtin_amdgcn_global_load_lds(
        (const __attribute__((address_space(1))) void*)g,
        (__attribute__((address_space(3))) void*)l, 16, 0, 0);
}

union BF4 { bf16 b[4]; uint2 u; };

// ---------------------------------------------------------------- PE table
// matches numpy f64 computation, cast to f32 at the end
__global__ void pe_kernel(float* __restrict__ pe) {
    int idx = blockIdx.x * 256 + threadIdx.x;
    if (idx >= kS * kD) return;
    int s = idx / kD, i = idx % kD;
    double dt = pow(10000.0, (double)(2 * (i / 2)) / (double)kD);
    double a  = (double)s / dt;
    pe[idx] = (float)((i & 1) ? cos(a) : sin(a));
}

// ---------------------------------------------------------------- embed + PE
__global__ __launch_bounds__(256) void embed_kernel(
    const int* __restrict__ tokens, const float* __restrict__ emb,
    const float* __restrict__ pe, float* __restrict__ xf, bf16* __restrict__ xb) {
    int row = blockIdx.x, t = threadIdx.x;
    int tok = tokens[row];
    const float4* ev = (const float4*)(emb + (size_t)tok * kD);
    const float4* pv = (const float4*)(pe + (size_t)(row % kS) * kD);
    float4 a = ev[t], b = pv[t];
    float4 v; v.x = a.x + b.x; v.y = a.y + b.y; v.z = a.z + b.z; v.w = a.w + b.w;
    ((float4*)(xf + (size_t)row * kD))[t] = v;
    BF4 p; p.b[0] = __float2bfloat16(v.x); p.b[1] = __float2bfloat16(v.y);
    p.b[2] = __float2bfloat16(v.z); p.b[3] = __float2bfloat16(v.w);
    *(uint2*)(xb + (size_t)row * kD + t * 4) = p.u;
}

// ------------------------------------------------ f32 [K][N] -> bf16 [N][K]
__global__ __launch_bounds__(256) void transpose_to_bf16(
    const float* __restrict__ in, bf16* __restrict__ out, int K, int N) {
    __shared__ float tile[64][65];
    size_t zoff = (size_t)blockIdx.z * K * N;
    int k0 = blockIdx.y * 64, n0 = blockIdx.x * 64;
    int t = threadIdx.x, r = t >> 6, c = t & 63;
#pragma unroll
    for (int it = 0; it < 16; ++it)
        tile[it * 4 + r][c] = in[zoff + (size_t)(k0 + it * 4 + r) * N + n0 + c];
    __syncthreads();
#pragma unroll
    for (int it = 0; it < 16; ++it)
        out[zoff + (size_t)(n0 + it * 4 + r) * K + k0 + c] =
            __float2bfloat16(tile[c][it * 4 + r]);
}

__global__ void concat_bias(const float* __restrict__ bq, const float* __restrict__ bk,
                            const float* __restrict__ bv, float* __restrict__ out) {
    int id = blockIdx.x * 256 + threadIdx.x;
    if (id >= 3 * kD) return;
    const float* src = (id < kD) ? bq : (id < 2 * kD) ? bk : bv;
    out[id] = src[id & (kD - 1)];
}

// ---------------------------------------------------------------- GEMM
// C[M,N] = A[M,K](bf16) @ Bt[N,K](bf16)^T + bias; optional ReLU; f32 or bf16 out.
// 128x128 tile, BK=32, 256 threads (4 waves, each 64x64 = 4x4 16x16 frags).
// m97 structure: global_load_lds width-16, 2-barrier K-loop.
template <bool RELU, bool OUT_BF16>
__global__ __launch_bounds__(256) void gemm_kernel(
    const bf16* __restrict__ A, const bf16* __restrict__ Bt,
    const float* __restrict__ bias, float* __restrict__ Cf, bf16* __restrict__ Cb,
    int M, int N, int K) {
    __shared__ bf16 As[128 * 32];
    __shared__ bf16 Bs[128 * 32];
    const int t = threadIdx.x;
    const int lane = t & 63, wave = t >> 6;
    const int wr = wave >> 1, wc = wave & 1;
    const int m0 = blockIdx.y * 128, n0 = blockIdx.x * 128;

    f32x4 acc[4][4] = {};

    const int srow = t >> 2;            // 0..63
    const int scol = (t & 3) * 8;       // 0,8,16,24
    const bf16* gA = A + (size_t)(m0 + srow) * K + scol;
    const bf16* gB = Bt + (size_t)(n0 + srow) * K + scol;
    char* lA = (char*)As + t * 16;      // = wave-base + lane*16 (linear LDS, m97)
    char* lB = (char*)Bs + t * 16;

    const int fr = lane & 15;
    const int koff = (lane >> 4) * 8;

    for (int k0 = 0; k0 < K; k0 += 32) {
        __syncthreads();                // consumers of previous tile done
        gload_lds16(gA, lA);
        gload_lds16(gA + (size_t)64 * K, lA + 4096);
        gload_lds16(gB, lB);
        gload_lds16(gB + (size_t)64 * K, lB + 4096);
        gA += 32; gB += 32;
        __syncthreads();                // compiler drains vmcnt(0) before s_barrier

        short8 fa[4], fb[4];
#pragma unroll
        for (int i = 0; i < 4; ++i) {
            fa[i] = *(const short8*)(As + (wr * 64 + i * 16 + fr) * 32 + koff);
            fb[i] = *(const short8*)(Bs + (wc * 64 + i * 16 + fr) * 32 + koff);
        }
#pragma unroll
        for (int i = 0; i < 4; ++i)
#pragma unroll
            for (int j = 0; j < 4; ++j)
                acc[i][j] = __builtin_amdgcn_mfma_f32_16x16x32_bf16(
                    fa[i], fb[j], acc[i][j], 0, 0, 0);
    }

    // D layout: col = lane&15, row = (lane>>4)*4 + reg  [m89/m91 verified]
    const int cr = (lane >> 4) * 4;
    const int cc = lane & 15;
#pragma unroll
    for (int i = 0; i < 4; ++i)
#pragma unroll
        for (int j = 0; j < 4; ++j) {
            int col = n0 + wc * 64 + j * 16 + cc;
            float bv = bias[col];
#pragma unroll
            for (int r = 0; r < 4; ++r) {
                int row = m0 + wr * 64 + i * 16 + cr + r;
                float v = acc[i][j][r] + bv;
                if (RELU) v = fmaxf(v, 0.f);
                if (OUT_BF16) Cb[(size_t)row * N + col] = __float2bfloat16(v);
                else          Cf[(size_t)row * N + col] = v;
            }
        }
}

// ---------------------------------------------------------------- attention
// one block per (b,h); qkv is [6400][3072] f32 (Q|K|V, col = h*64+e within each)
__global__ __launch_bounds__(256) void attn_kernel(
    const float* __restrict__ qkv, bf16* __restrict__ ctx) {
    __shared__ float Kt[64][101];   // K transposed, padded (bank-free both axes)
    __shared__ float Vs[kS][64];
    __shared__ float aw[4][kS];
    int b = blockIdx.x >> 4, h = blockIdx.x & 15;
    int t = threadIdx.x, lane = t & 63, w = t >> 6;
    const size_t base = (size_t)b * kS * 3072 + h * 64;

    for (int it = 0; it < 25; ++it) {
        int idx = it * 256 + t;
        int s = idx >> 6, e = idx & 63;
        Kt[e][s] = qkv[base + (size_t)s * 3072 + 1024 + e];
        Vs[s][e] = qkv[base + (size_t)s * 3072 + 2048 + e];
    }
    __syncthreads();

    const int l2 = (lane < 36) ? 64 + lane : 99;   // keys 64..99 (lane>=36 masked)
    for (int q = w; q < kS; q += 4) {
        float qv = qkv[base + (size_t)q * 3072 + lane];
        float s1 = 0.f, s2 = 0.f;
#pragma unroll
        for (int d = 0; d < 64; ++d) {
            float qs = __shfl(qv, d);          // compile-time d -> v_readlane
            s1 = fmaf(qs, Kt[d][lane], s1);
            s2 = fmaf(qs, Kt[d][l2], s2);
        }
        s1 *= 0.125f; s2 *= 0.125f;            // 1/sqrt(64)
        float m = fmaxf(s1, (lane < 36) ? s2 : -__builtin_inff());
#pragma unroll
        for (int off = 32; off; off >>= 1) m = fmaxf(m, __shfl_xor(m, off));
        float p1 = __expf(s1 - m);
        float p2 = (lane < 36) ? __expf(s2 - m) : 0.f;
        float sum = p1 + p2;
#pragma unroll
        for (int off = 32; off; off >>= 1) sum += __shfl_xor(sum, off);
        float inv = 1.f / sum;
        aw[w][lane] = p1 * inv;
        if (lane < 36) aw[w][64 + lane] = p2 * inv;
        float c = 0.f;
#pragma unroll 4
        for (int k = 0; k < kS; ++k) c = fmaf(aw[w][k], Vs[k][lane], c);
        ctx[((size_t)b * kS + q) * kD + h * 64 + lane] = __float2bfloat16(c);
    }
}

// ---------------------------------------------------------------- add + LN
__global__ __launch_bounds__(256) void add_ln_kernel(
    const float* __restrict__ a, const float* __restrict__ r,
    const float* __restrict__ gamma, const float* __restrict__ beta,
    float* __restrict__ outf, bf16* __restrict__ outb) {
    __shared__ float red[10];
    int row = blockIdx.x, t = threadIdx.x, lane = t & 63, w = t >> 6;
    const float4 va = ((const float4*)(a + (size_t)row * kD))[t];
    const float4 vr = ((const float4*)(r + (size_t)row * kD))[t];
    float4 x; x.x = va.x + vr.x; x.y = va.y + vr.y; x.z = va.z + vr.z; x.w = va.w + vr.w;
    float s  = x.x + x.y + x.z + x.w;
    float ss = x.x * x.x + x.y * x.y + x.z * x.z + x.w * x.w;
#pragma unroll
    for (int off = 32; off; off >>= 1) {
        s += __shfl_xor(s, off); ss += __shfl_xor(ss, off);
    }
    if (lane == 0) { red[w] = s; red[4 + w] = ss; }
    __syncthreads();
    if (t == 0) {
        float S = red[0] + red[1] + red[2] + red[3];
        float Q = red[4] + red[5] + red[6] + red[7];
        float mean = S / kD;
        float var  = Q / kD - mean * mean;
        red[8] = mean; red[9] = rsqrtf(var + 1e-6f);
    }
    __syncthreads();
    float mean = red[8], rstd = red[9];
    const float4 g  = ((const float4*)gamma)[t];
    const float4 be = ((const float4*)beta)[t];
    float4 o;
    o.x = g.x * ((x.x - mean) * rstd) + be.x;
    o.y = g.y * ((x.y - mean) * rstd) + be.y;
    o.z = g.z * ((x.z - mean) * rstd) + be.z;
    o.w = g.w * ((x.w - mean) * rstd) + be.w;
    ((float4*)(outf + (size_t)row * kD))[t] = o;
    if (outb) {
        BF4 p; p.b[0] = __float2bfloat16(o.x); p.b[1] = __float2bfloat16(o.y);
        p.b[2] = __float2bfloat16(o.z); p.b[3] = __float2bfloat16(o.w);
        *(uint2*)(outb + (size_t)row * kD + t * 4) = p.u;
    }
}

// ---------------------------------------------------------------- launcher
// Workspace layout (byte offsets), peak 182,464,512 B (~174 MiB).
// Lifetime audit:
//  1 pe_kernel  -> pe   @104,857,600 (inside future qkv tail; dead after embed)
//  2 embed      -> xf @0, xb @156,250,112
//  3 repacks    -> wqkvt/wot/w1t/w2t/bqkv @131,072,000..156,250,112
//  4 QKV gemm   -> qkv @52,428,800 (overwrites dead pe)
//  5 attn       -> ctx into xb (x-bf16 dead)
//  6 Wo gemm    -> attout @26,214,400
//  7 LN1        -> x1f @52,428,800 (qkv dead), x1b @169,357,312
//  8 FFN1       -> hbuf @0 (xf+attout dead, exactly 52,428,800 B)
//  9 FFN2       -> ff @78,643,200 (inside dead qkv, above live x1f)
// 10 LN2        -> d_out
extern "C" void kernel_launch(void* const* d_in, const int* in_sizes, int n_in,
                              void* d_out, int out_size, void* d_ws, size_t ws_size,
                              hipStream_t stream) {
    const int*   tokens = (const int*)d_in[0];
    const float* emb    = (const float*)d_in[1];
    const float* Wq     = (const float*)d_in[2];
    const float* bq     = (const float*)d_in[3];
    const float* Wk     = (const float*)d_in[4];
    const float* bk     = (const float*)d_in[5];
    const float* Wv     = (const float*)d_in[6];
    const float* bv     = (const float*)d_in[7];
    const float* Wo     = (const float*)d_in[8];
    const float* bo     = (const float*)d_in[9];
    const float* W1     = (const float*)d_in[10];
    const float* b1     = (const float*)d_in[11];
    const float* W2     = (const float*)d_in[12];
    const float* b2     = (const float*)d_in[13];
    const float* g1     = (const float*)d_in[14];
    const float* be1    = (const float*)d_in[15];
    const float* g2     = (const float*)d_in[16];
    const float* be2    = (const float*)d_in[17];

    char* ws = (char*)d_ws;
    float* xf     = (float*)(ws + 0);
    float* attout = (float*)(ws + 26214400);
    bf16*  hbuf   = (bf16*) (ws + 0);           // aliases xf+attout (dead by FFN1)
    float* qkv    = (float*)(ws + 52428800);
    float* x1f    = (float*)(ws + 52428800);    // aliases qkv[0:26.2M] (dead by LN1)
    float* ff     = (float*)(ws + 78643200);    // aliases qkv[26.2M:52.4M]
    float* pe     = (float*)(ws + 104857600);   // aliases qkv tail (dead by gemm)
    bf16*  wqkvt  = (bf16*) (ws + 131072000);   // [3072][1024]
    bf16*  wot    = (bf16*) (ws + 137363456);   // [1024][1024]
    bf16*  w1t    = (bf16*) (ws + 139460608);   // [4096][1024]
    bf16*  w2t    = (bf16*) (ws + 147849216);   // [1024][4096]
    float* bqkv   = (float*)(ws + 156237824);   // [3072]
    bf16*  xb     = (bf16*) (ws + 156250112);   // x bf16, later ctx
    bf16*  x1b    = (bf16*) (ws + 169357312);   // x1 bf16

    pe_kernel<<<400, 256, 0, stream>>>(pe);
    embed_kernel<<<kRows, 256, 0, stream>>>(tokens, emb, pe, xf, xb);

    transpose_to_bf16<<<dim3(1, 16, 16), 256, 0, stream>>>(Wq, wqkvt,               1024, 64);
    transpose_to_bf16<<<dim3(1, 16, 16), 256, 0, stream>>>(Wk, wqkvt + 1024 * 1024, 1024, 64);
    transpose_to_bf16<<<dim3(1, 16, 16), 256, 0, stream>>>(Wv, wqkvt + 2048 * 1024, 1024, 64);
    transpose_to_bf16<<<dim3(16, 16, 1), 256, 0, stream>>>(Wo, wot, 1024, 1024);
    transpose_to_bf16<<<dim3(64, 16, 1), 256, 0, stream>>>(W1, w1t, 1024, 4096);
    transpose_to_bf16<<<dim3(16, 64, 1), 256, 0, stream>>>(W2, w2t, 4096, 1024);
    concat_bias<<<12, 256, 0, stream>>>(bq, bk, bv, bqkv);

    // QKV: [6400,3072]
    gemm_kernel<false, false><<<dim3(24, 50), 256, 0, stream>>>(
        xb, wqkvt, bqkv, qkv, nullptr, kRows, 3072, 1024);
    // attention -> ctx (bf16, concat-head layout) into xb
    attn_kernel<<<kB * kH, 256, 0, stream>>>(qkv, xb);
    // Wo: [6400,1024]
    gemm_kernel<false, false><<<dim3(8, 50), 256, 0, stream>>>(
        xb, wot, bo, attout, nullptr, kRows, 1024, 1024);
    add_ln_kernel<<<kRows, 256, 0, stream>>>(attout, xf, g1, be1, x1f, x1b);
    // FFN1: [6400,4096] + bias + ReLU -> bf16
    gemm_kernel<true, true><<<dim3(32, 50), 256, 0, stream>>>(
        x1b, w1t, b1, nullptr, hbuf, kRows, 4096, 1024);
    // FFN2: [6400,1024]
    gemm_kernel<false, false><<<dim3(8, 50), 256, 0, stream>>>(
        hbuf, w2t, b2, ff, nullptr, kRows, 1024, 4096);
    add_ln_kernel<<<kRows, 256, 0, stream>>>(ff, x1f, g2, be2, (float*)d_out, nullptr);
}

// Round 3
// 565.343 us; speedup vs baseline: 1.2571x; 1.2571x over previous
//
#include <hip/hip_runtime.h>
#include <hip/hip_bf16.h>
#include <math.h>

typedef __hip_bfloat16 bf16;
typedef __attribute__((ext_vector_type(8))) short short8;
typedef __attribute__((ext_vector_type(4))) float f32x4;

static constexpr int kB = 64;
static constexpr int kS = 100;
static constexpr int kD = 1024;
static constexpr int kH = 16;
static constexpr int kF = 4096;
static constexpr int kRows = kB * kS;  // 6400

// ---------------------------------------------------------------- helpers
__device__ __forceinline__ void gload_lds16(const void* g, void* l) {
    __builtin_amdgcn_global_load_lds(
        (const __attribute__((address_space(1))) void*)g,
        (__attribute__((address_space(3))) void*)l, 16, 0, 0);
}

union BF4 { bf16 b[4]; uint2 u; };

// ---------------------------------------------------------------- PE table
__global__ void pe_kernel(float* __restrict__ pe) {
    int idx = blockIdx.x * 256 + threadIdx.x;
    if (idx >= kS * kD) return;
    int s = idx / kD, i = idx % kD;
    double dt = pow(10000.0, (double)(2 * (i / 2)) / (double)kD);
    double a  = (double)s / dt;
    pe[idx] = (float)((i & 1) ? cos(a) : sin(a));
}

// ---------------------------------------------------------------- embed + PE
__global__ __launch_bounds__(256) void embed_kernel(
    const int* __restrict__ tokens, const float* __restrict__ emb,
    const float* __restrict__ pe, float* __restrict__ xf, bf16* __restrict__ xb) {
    int row = blockIdx.x, t = threadIdx.x;
    int tok = tokens[row];
    const float4* ev = (const float4*)(emb + (size_t)tok * kD);
    const float4* pv = (const float4*)(pe + (size_t)(row % kS) * kD);
    float4 a = ev[t], b = pv[t];
    float4 v; v.x = a.x + b.x; v.y = a.y + b.y; v.z = a.z + b.z; v.w = a.w + b.w;
    ((float4*)(xf + (size_t)row * kD))[t] = v;
    BF4 p; p.b[0] = __float2bfloat16(v.x); p.b[1] = __float2bfloat16(v.y);
    p.b[2] = __float2bfloat16(v.z); p.b[3] = __float2bfloat16(v.w);
    *(uint2*)(xb + (size_t)row * kD + t * 4) = p.u;
}

// ------------------------------------------------ f32 [K][N] -> bf16 [N][K]
__global__ __launch_bounds__(256) void transpose_to_bf16(
    const float* __restrict__ in, bf16* __restrict__ out, int K, int N) {
    __shared__ float tile[64][65];
    size_t zoff = (size_t)blockIdx.z * K * N;
    int k0 = blockIdx.y * 64, n0 = blockIdx.x * 64;
    int t = threadIdx.x, r = t >> 6, c = t & 63;
#pragma unroll
    for (int it = 0; it < 16; ++it)
        tile[it * 4 + r][c] = in[zoff + (size_t)(k0 + it * 4 + r) * N + n0 + c];
    __syncthreads();
#pragma unroll
    for (int it = 0; it < 16; ++it)
        out[zoff + (size_t)(n0 + it * 4 + r) * K + k0 + c] =
            __float2bfloat16(tile[c][it * 4 + r]);
}

__global__ void concat_bias(const float* __restrict__ bq, const float* __restrict__ bk,
                            const float* __restrict__ bv, float* __restrict__ out) {
    int id = blockIdx.x * 256 + threadIdx.x;
    if (id >= 3 * kD) return;
    const float* src = (id < kD) ? bq : (id < 2 * kD) ? bk : bv;
    out[id] = src[id & (kD - 1)];
}

// ---------------------------------------------------------------- GEMM
// C[M,N] = A[M,K](bf16) @ Bt[N,K](bf16)^T + bias; optional ReLU; f32 or bf16 out.
// 128x128 tile, BK=32, 256 threads. m97 structure (global_load_lds w16).
template <bool RELU, bool OUT_BF16>
__global__ __launch_bounds__(256) void gemm_kernel(
    const bf16* __restrict__ A, const bf16* __restrict__ Bt,
    const float* __restrict__ bias, float* __restrict__ Cf, bf16* __restrict__ Cb,
    int M, int N, int K) {
    __shared__ bf16 As[128 * 32];
    __shared__ bf16 Bs[128 * 32];
    const int t = threadIdx.x;
    const int lane = t & 63, wave = t >> 6;
    const int wr = wave >> 1, wc = wave & 1;
    const int m0 = blockIdx.y * 128, n0 = blockIdx.x * 128;

    f32x4 acc[4][4] = {};

    const int srow = t >> 2;
    const int scol = (t & 3) * 8;
    const bf16* gA = A + (size_t)(m0 + srow) * K + scol;
    const bf16* gB = Bt + (size_t)(n0 + srow) * K + scol;
    char* lA = (char*)As + t * 16;
    char* lB = (char*)Bs + t * 16;

    const int fr = lane & 15;
    const int koff = (lane >> 4) * 8;

    for (int k0 = 0; k0 < K; k0 += 32) {
        __syncthreads();
        gload_lds16(gA, lA);
        gload_lds16(gA + (size_t)64 * K, lA + 4096);
        gload_lds16(gB, lB);
        gload_lds16(gB + (size_t)64 * K, lB + 4096);
        gA += 32; gB += 32;
        __syncthreads();

        short8 fa[4], fb[4];
#pragma unroll
        for (int i = 0; i < 4; ++i) {
            fa[i] = *(const short8*)(As + (wr * 64 + i * 16 + fr) * 32 + koff);
            fb[i] = *(const short8*)(Bs + (wc * 64 + i * 16 + fr) * 32 + koff);
        }
#pragma unroll
        for (int i = 0; i < 4; ++i)
#pragma unroll
            for (int j = 0; j < 4; ++j)
                acc[i][j] = __builtin_amdgcn_mfma_f32_16x16x32_bf16(
                    fa[i], fb[j], acc[i][j], 0, 0, 0);
    }

    const int cr = (lane >> 4) * 4;
    const int cc = lane & 15;
#pragma unroll
    for (int i = 0; i < 4; ++i)
#pragma unroll
        for (int j = 0; j < 4; ++j) {
            int col = n0 + wc * 64 + j * 16 + cc;
            float bv = bias[col];
#pragma unroll
            for (int r = 0; r < 4; ++r) {
                int row = m0 + wr * 64 + i * 16 + cr + r;
                float v = acc[i][j][r] + bv;
                if (RELU) v = fmaxf(v, 0.f);
                if (OUT_BF16) Cb[(size_t)row * N + col] = __float2bfloat16(v);
                else          Cf[(size_t)row * N + col] = v;
            }
        }
}

// ---------------------------------------------------------------- MFMA attention
// one block per (b,h). qkvb: bf16 [6400][3072] (Q|K|V, each col = h*64+e).
// Score cols padded to 112 (7 frags), rows/k padded to 128.
// LDS: Ks[112][64] swz, Vt[64][128] swz (V transposed), Ps[128][128] swz = 62KB.
__global__ __launch_bounds__(256) void attn_mfma_kernel(
    const bf16* __restrict__ qkvb, bf16* __restrict__ ctx) {
    __shared__ bf16 Ks[112 * 64];
    __shared__ bf16 Vt[64 * 128];
    __shared__ bf16 Ps[128 * 128];
    const int b = blockIdx.x >> 4, h = blockIdx.x & 15;
    const int t = threadIdx.x, lane = t & 63, w = t >> 6;
    const int fr = lane & 15, qq = lane >> 4;
    const size_t rbase = (size_t)b * kS * 3072 + (size_t)h * 64;

    // zero pad regions (addresses disjoint from staged data: XOR swizzle is bijective)
    for (int i = t; i < 64 * 14; i += 256) {          // Vt k=100..127 := 0
        int e = i / 14, kk = 100 + (i % 14) * 2;
        *(unsigned*)((char*)Vt + e * 256 + ((kk * 2) ^ ((e & 7) << 4))) = 0u;
    }
    for (int i = t; i < 128 * 8; i += 256) {          // Ps cols 112..127 := 0
        int r = i / 8, c = 112 + (i % 8) * 2;
        *(unsigned*)((char*)Ps + r * 256 + ((c * 2) ^ ((r & 7) << 4))) = 0u;
    }
    // stage K rows (swizzled) + V transposed (swizzled). K pad rows garbage=OK (masked).
    for (int it = 0; it < 4; ++it) {
        int s = it * 32 + (t >> 3);
        if (s < kS) {
            int e0 = (t & 7) * 8;
            const bf16* kr = qkvb + rbase + (size_t)s * 3072 + 1024 + e0;
            short8 kv = *(const short8*)kr;
            *(short8*)((char*)Ks + s * 128 + ((e0 * 2) ^ ((s & 7) << 4))) = kv;
            short8 vv = *(const short8*)(kr + 1024);
#pragma unroll
            for (int i2 = 0; i2 < 8; ++i2) {
                int e = e0 + i2;
                *(unsigned short*)((char*)Vt + e * 256 + ((s * 2) ^ ((e & 7) << 4))) =
                    ((unsigned short*)&vv)[i2];
            }
        }
    }
    // Q fragments straight from global (A-frag: row=lane&15, k-chunk=(lane>>4)*8)
    short8 qa[2][2];
#pragma unroll
    for (int rt = 0; rt < 2; ++rt)
#pragma unroll
        for (int ks = 0; ks < 2; ++ks) {
            int q = 32 * w + 16 * rt + fr; q = q < kS ? q : kS - 1;  // clamp (OOB guard)
            qa[rt][ks] = *(const short8*)(qkvb + rbase + (size_t)q * 3072 + 32 * ks + 8 * qq);
        }
    __syncthreads();

    short8 kb[7][2];
#pragma unroll
    for (int j = 0; j < 7; ++j)
#pragma unroll
        for (int ks = 0; ks < 2; ++ks)
            kb[j][ks] = *(const short8*)((char*)Ks + (16 * j + fr) * 128 +
                                         ((64 * ks + 16 * qq) ^ ((fr & 7) << 4)));

    f32x4 sc[2][7] = {};
#pragma unroll
    for (int rt = 0; rt < 2; ++rt)
#pragma unroll
        for (int j = 0; j < 7; ++j)
#pragma unroll
            for (int ks = 0; ks < 2; ++ks)
                sc[rt][j] = __builtin_amdgcn_mfma_f32_16x16x32_bf16(
                    qa[rt][ks], kb[j][ks], sc[rt][j], 0, 0, 0);

    // row softmax. D layout: col=lane&15(=fr), row=qq*4+r; 16-lane group shares rows.
    float inv_l[2][4];
#pragma unroll
    for (int rt = 0; rt < 2; ++rt)
#pragma unroll
        for (int r = 0; r < 4; ++r) {
            float v[7];
#pragma unroll
            for (int j = 0; j < 7; ++j) v[j] = sc[rt][j][r] * 0.125f;
            if (fr >= 4) v[6] = -INFINITY;            // cols 100..111 masked
            float m = v[0];
#pragma unroll
            for (int j = 1; j < 7; ++j) m = fmaxf(m, v[j]);
#pragma unroll
            for (int off = 8; off; off >>= 1) m = fmaxf(m, __shfl_xor(m, off));
            int row = 32 * w + 16 * rt + qq * 4 + r;
            float s = 0.f;
#pragma unroll
            for (int j = 0; j < 7; ++j) {
                float p = __expf(v[j] - m);           // masked -> exp(-inf)=0
                s += p;
                *(bf16*)((char*)Ps + row * 256 + (((16 * j + fr) * 2) ^ ((row & 7) << 4))) =
                    __float2bfloat16(p);
            }
#pragma unroll
            for (int off = 8; off; off >>= 1) s += __shfl_xor(s, off);
            inv_l[rt][r] = 1.f / s;
        }
    __syncthreads();   // order P ds_writes before cross-reads (safety)

    short8 pa[2][4];
#pragma unroll
    for (int rt = 0; rt < 2; ++rt)
#pragma unroll
        for (int ks = 0; ks < 4; ++ks) {
            int row = 32 * w + 16 * rt + fr;
            pa[rt][ks] = *(const short8*)((char*)Ps + row * 256 +
                                          ((64 * ks + 16 * qq) ^ ((fr & 7) << 4)));
        }
#pragma unroll
    for (int e = 0; e < 4; ++e) {
        short8 vb[4];
#pragma unroll
        for (int ks = 0; ks < 4; ++ks)
            vb[ks] = *(const short8*)((char*)Vt + (16 * e + fr) * 256 +
                                      ((64 * ks + 16 * qq) ^ ((fr & 7) << 4)));
#pragma unroll
        for (int rt = 0; rt < 2; ++rt) {
            f32x4 o = {};
#pragma unroll
            for (int ks = 0; ks < 4; ++ks)
                o = __builtin_amdgcn_mfma_f32_16x16x32_bf16(pa[rt][ks], vb[ks], o, 0, 0, 0);
#pragma unroll
            for (int r = 0; r < 4; ++r) {
                int q = 32 * w + 16 * rt + qq * 4 + r;
                if (q < kS)
                    ctx[((size_t)b * kS + q) * kD + h * 64 + 16 * e + fr] =
                        __float2bfloat16(o[r] * inv_l[rt][r]);
            }
        }
    }
}

// ---------------------------------------------------------------- add + LN
__global__ __launch_bounds__(256) void add_ln_kernel(
    const float* __restrict__ a, const float* __restrict__ r,
    const float* __restrict__ gamma, const float* __restrict__ beta,
    float* __restrict__ outf, bf16* __restrict__ outb) {
    __shared__ float red[10];
    int row = blockIdx.x, t = threadIdx.x, lane = t & 63, w = t >> 6;
    const float4 va = ((const float4*)(a + (size_t)row * kD))[t];
    const float4 vr = ((const float4*)(r + (size_t)row * kD))[t];
    float4 x; x.x = va.x + vr.x; x.y = va.y + vr.y; x.z = va.z + vr.z; x.w = va.w + vr.w;
    float s  = x.x + x.y + x.z + x.w;
    float ss = x.x * x.x + x.y * x.y + x.z * x.z + x.w * x.w;
#pragma unroll
    for (int off = 32; off; off >>= 1) {
        s += __shfl_xor(s, off); ss += __shfl_xor(ss, off);
    }
    if (lane == 0) { red[w] = s; red[4 + w] = ss; }
    __syncthreads();
    if (t == 0) {
        float S = red[0] + red[1] + red[2] + red[3];
        float Q = red[4] + red[5] + red[6] + red[7];
        float mean = S / kD;
        float var  = Q / kD - mean * mean;
        red[8] = mean; red[9] = rsqrtf(var + 1e-6f);
    }
    __syncthreads();
    float mean = red[8], rstd = red[9];
    const float4 g  = ((const float4*)gamma)[t];
    const float4 be = ((const float4*)beta)[t];
    float4 o;
    o.x = g.x * ((x.x - mean) * rstd) + be.x;
    o.y = g.y * ((x.y - mean) * rstd) + be.y;
    o.z = g.z * ((x.z - mean) * rstd) + be.z;
    o.w = g.w * ((x.w - mean) * rstd) + be.w;
    ((float4*)(outf + (size_t)row * kD))[t] = o;
    if (outb) {
        BF4 p; p.b[0] = __float2bfloat16(o.x); p.b[1] = __float2bfloat16(o.y);
        p.b[2] = __float2bfloat16(o.z); p.b[3] = __float2bfloat16(o.w);
        *(uint2*)(outb + (size_t)row * kD + t * 4) = p.u;
    }
}

// ---------------------------------------------------------------- launcher
// Workspace layout (peak 169,766,912 B < round-2's proven 182.4MB):
//  xf      @0            26,214,400  [embed -> LN1]
//  xb/ctx  @26,214,400   13,107,200  [embed->QKV gemm; attn->Wo gemm]
//  qkvb    @39,321,600   39,321,600  [QKV gemm -> attn]
//  hbuf    @0            52,428,800  [FFN1 -> FFN2] (aliases xf+xb+qkvb head, all dead)
//  attout  @78,643,200   26,214,400  [Wo -> LN1]; ff aliases same [FFN2 -> LN2]
//  x1f     @104,857,600  26,214,400  [LN1 -> LN2]
//  x1b     @131,072,000  13,107,200  [LN1 -> FFN1]
//  pe/weights/bias @144,179,200 .. 169,766,912 (resident from repack on)
extern "C" void kernel_launch(void* const* d_in, const int* in_sizes, int n_in,
                              void* d_out, int out_size, void* d_ws, size_t ws_size,
                              hipStream_t stream) {
    const int*   tokens = (const int*)d_in[0];
    const float* emb    = (const float*)d_in[1];
    const float* Wq     = (const float*)d_in[2];
    const float* bq     = (const float*)d_in[3];
    const float* Wk     = (const float*)d_in[4];
    const float* bk     = (const float*)d_in[5];
    const float* Wv     = (const float*)d_in[6];
    const float* bv     = (const float*)d_in[7];
    const float* Wo     = (const float*)d_in[8];
    const float* bo     = (const float*)d_in[9];
    const float* W1     = (const float*)d_in[10];
    const float* b1     = (const float*)d_in[11];
    const float* W2     = (const float*)d_in[12];
    const float* b2     = (const float*)d_in[13];
    const float* g1     = (const float*)d_in[14];
    const float* be1    = (const float*)d_in[15];
    const float* g2     = (const float*)d_in[16];
    const float* be2    = (const float*)d_in[17];

    char* ws = (char*)d_ws;
    float* xf     = (float*)(ws + 0);
    bf16*  xb     = (bf16*) (ws + 26214400);     // x bf16, later ctx
    bf16*  qkvb   = (bf16*) (ws + 39321600);     // [6400][3072] bf16
    bf16*  hbuf   = (bf16*) (ws + 0);            // FFN1 out (aliases dead buffers)
    float* attout = (float*)(ws + 78643200);
    float* ff     = (float*)(ws + 78643200);     // aliases attout (dead by FFN2)
    float* x1f    = (float*)(ws + 104857600);
    bf16*  x1b    = (bf16*) (ws + 131072000);
    float* pe     = (float*)(ws + 144179200);
    bf16*  wqkvt  = (bf16*) (ws + 144588800);    // [3072][1024]
    bf16*  wot    = (bf16*) (ws + 150880256);    // [1024][1024]
    bf16*  w1t    = (bf16*) (ws + 152977408);    // [4096][1024]
    bf16*  w2t    = (bf16*) (ws + 161366016);    // [1024][4096]
    float* bqkv   = (float*)(ws + 169754624);    // [3072]

    pe_kernel<<<400, 256, 0, stream>>>(pe);
    embed_kernel<<<kRows, 256, 0, stream>>>(tokens, emb, pe, xf, xb);

    transpose_to_bf16<<<dim3(1, 16, 16), 256, 0, stream>>>(Wq, wqkvt,               1024, 64);
    transpose_to_bf16<<<dim3(1, 16, 16), 256, 0, stream>>>(Wk, wqkvt + 1024 * 1024, 1024, 64);
    transpose_to_bf16<<<dim3(1, 16, 16), 256, 0, stream>>>(Wv, wqkvt + 2048 * 1024, 1024, 64);
    transpose_to_bf16<<<dim3(16, 16, 1), 256, 0, stream>>>(Wo, wot, 1024, 1024);
    transpose_to_bf16<<<dim3(64, 16, 1), 256, 0, stream>>>(W1, w1t, 1024, 4096);
    transpose_to_bf16<<<dim3(16, 64, 1), 256, 0, stream>>>(W2, w2t, 4096, 1024);
    concat_bias<<<12, 256, 0, stream>>>(bq, bk, bv, bqkv);

    // QKV: [6400,3072] -> bf16
    gemm_kernel<false, true><<<dim3(24, 50), 256, 0, stream>>>(
        xb, wqkvt, bqkv, nullptr, qkvb, kRows, 3072, 1024);
    // attention -> ctx (bf16, concat-head layout) into xb
    attn_mfma_kernel<<<kB * kH, 256, 0, stream>>>(qkvb, xb);
    // Wo: [6400,1024]
    gemm_kernel<false, false><<<dim3(8, 50), 256, 0, stream>>>(
        xb, wot, bo, attout, nullptr, kRows, 1024, 1024);
    add_ln_kernel<<<kRows, 256, 0, stream>>>(attout, xf, g1, be1, x1f, x1b);
    // FFN1: [6400,4096] + bias + ReLU -> bf16
    gemm_kernel<true, true><<<dim3(32, 50), 256, 0, stream>>>(
        x1b, w1t, b1, nullptr, hbuf, kRows, 4096, 1024);
    // FFN2: [6400,1024]
    gemm_kernel<false, false><<<dim3(8, 50), 256, 0, stream>>>(
        hbuf, w2t, b2, ff, nullptr, kRows, 1024, 4096);
    add_ln_kernel<<<kRows, 256, 0, stream>>>(ff, x1f, g2, be2, (float*)d_out, nullptr);
}

// Round 4
// 529.692 us; speedup vs baseline: 1.3418x; 1.0673x over previous
//
#include <hip/hip_runtime.h>
#include <hip/hip_bf16.h>
#include <math.h>

typedef __hip_bfloat16 bf16;
typedef __attribute__((ext_vector_type(8))) short short8;
typedef __attribute__((ext_vector_type(4))) float f32x4;

static constexpr int kB = 64;
static constexpr int kS = 100;
static constexpr int kD = 1024;
static constexpr int kH = 16;
static constexpr int kF = 4096;
static constexpr int kRows = kB * kS;  // 6400

// ---------------------------------------------------------------- helpers
__device__ __forceinline__ void gload_lds16(const void* g, void* l) {
    __builtin_amdgcn_global_load_lds(
        (const __attribute__((address_space(1))) void*)g,
        (__attribute__((address_space(3))) void*)l, 16, 0, 0);
}

union BF4 { bf16 b[4]; uint2 u; };

// ---------------------------------------------------------------- prep
// One launch: all weight transposes (f32 [K][N] -> bf16 [N][K]), bias concat,
// PE table. Block ranges:
//   [0,768)      Wq/Wk/Wv per-head transpose (3 x 16 heads x 16 k-tiles)
//   [768,1024)   Wo   (256 tiles)
//   [1024,2048)  W1   (1024 tiles)
//   [2048,3072)  W2   (1024 tiles)
//   [3072,3084)  bias concat (3072 elems)
//   [3084,3484)  PE table (102400 elems, f64 math)
__global__ __launch_bounds__(256) void prep_kernel(
    const float* __restrict__ Wq, const float* __restrict__ Wk,
    const float* __restrict__ Wv, const float* __restrict__ Wo,
    const float* __restrict__ W1, const float* __restrict__ W2,
    const float* __restrict__ bq, const float* __restrict__ bk,
    const float* __restrict__ bv,
    bf16* __restrict__ wqkvt, bf16* __restrict__ wot,
    bf16* __restrict__ w1t, bf16* __restrict__ w2t,
    float* __restrict__ bqkv, float* __restrict__ pe) {
    const int tb = blockIdx.x, t = threadIdx.x;
    if (tb < 3072) {
        __shared__ float tile[64][65];
        const float* src; bf16* dst; int N, ldd, tid;
        if (tb < 768) {            // qkv heads: each [1024][64], dst stride 1024
            int wsel = tb / 256, rem = tb % 256, h = rem >> 4;
            tid = rem & 15;
            src = (wsel == 0 ? Wq : wsel == 1 ? Wk : Wv) + (size_t)h * 65536;
            dst = wqkvt + (size_t)wsel * 1024 * 1024 + (size_t)h * 65536;
            N = 64; ldd = 1024;
        } else if (tb < 1024) { tid = tb - 768;  src = Wo; dst = wot; N = 1024; ldd = 1024; }
        else if (tb < 2048)   { tid = tb - 1024; src = W1; dst = w1t; N = 4096; ldd = 1024; }
        else                  { tid = tb - 2048; src = W2; dst = w2t; N = 1024; ldd = 4096; }
        const int ntx = N >> 6;
        const int k0 = (tid / ntx) * 64, n0 = (tid % ntx) * 64;
        const int r = t >> 6, c = t & 63;
#pragma unroll
        for (int it = 0; it < 16; ++it)
            tile[it * 4 + r][c] = src[(size_t)(k0 + it * 4 + r) * N + n0 + c];
        __syncthreads();
#pragma unroll
        for (int it = 0; it < 16; ++it)
            dst[(size_t)(n0 + it * 4 + r) * ldd + k0 + c] =
                __float2bfloat16(tile[c][it * 4 + r]);
    } else if (tb < 3084) {        // bias concat
        int id = (tb - 3072) * 256 + t;
        const float* src = (id < kD) ? bq : (id < 2 * kD) ? bk : bv;
        bqkv[id] = src[id & (kD - 1)];
    } else {                       // PE table (f64, matches numpy)
        int idx = (tb - 3084) * 256 + t;
        int s = idx / kD, i = idx % kD;
        double dt = pow(10000.0, (double)(2 * (i / 2)) / (double)kD);
        double a  = (double)s / dt;
        pe[idx] = (float)((i & 1) ? cos(a) : sin(a));
    }
}

// ---------------------------------------------------------------- embed + PE
__global__ __launch_bounds__(256) void embed_kernel(
    const int* __restrict__ tokens, const float* __restrict__ emb,
    const float* __restrict__ pe, float* __restrict__ xf, bf16* __restrict__ xb) {
    int row = blockIdx.x, t = threadIdx.x;
    int tok = tokens[row];
    const float4* ev = (const float4*)(emb + (size_t)tok * kD);
    const float4* pv = (const float4*)(pe + (size_t)(row % kS) * kD);
    float4 a = ev[t], b = pv[t];
    float4 v; v.x = a.x + b.x; v.y = a.y + b.y; v.z = a.z + b.z; v.w = a.w + b.w;
    ((float4*)(xf + (size_t)row * kD))[t] = v;
    BF4 p; p.b[0] = __float2bfloat16(v.x); p.b[1] = __float2bfloat16(v.y);
    p.b[2] = __float2bfloat16(v.z); p.b[3] = __float2bfloat16(v.w);
    *(uint2*)(xb + (size_t)row * kD + t * 4) = p.u;
}

// ---------------------------------------------------------------- GEMM
// C[M,N] = A[M,K] @ Bt[N,K]^T + bias (z==0 only); optional ReLU; f32/bf16 out.
// 128x128 tile, BK=32, 256 threads. Double-buffered LDS prefetch (one barrier
// per K-step, vmcnt drained after compute -> latency hidden). XCD-chunked
// swizzle: blocks on one XCD get a contiguous 2D chunk (8-col groups, x-fast)
// so A/B panels become L2-resident. gridDim.z = split-K slices.
#define GEMM_COMPUTE(BUF)                                                        \
    do {                                                                         \
        short8 fa[4], fb[4];                                                     \
        _Pragma("unroll") for (int i = 0; i < 4; ++i) {                          \
            fa[i] = *(const short8*)(As[BUF] + (wr * 64 + i * 16 + fr) * 32 + koff); \
            fb[i] = *(const short8*)(Bs[BUF] + (wc * 64 + i * 16 + fr) * 32 + koff); \
        }                                                                        \
        _Pragma("unroll") for (int i = 0; i < 4; ++i)                            \
            _Pragma("unroll") for (int j = 0; j < 4; ++j)                        \
                acc[i][j] = __builtin_amdgcn_mfma_f32_16x16x32_bf16(             \
                    fa[i], fb[j], acc[i][j], 0, 0, 0);                           \
    } while (0)

template <bool RELU, bool OUT_BF16>
__global__ __launch_bounds__(256) void gemm_kernel(
    const bf16* __restrict__ A, const bf16* __restrict__ Bt,
    const float* __restrict__ bias, float* __restrict__ Cf, bf16* __restrict__ Cb,
    int M, int N, int Kfull, int Kslice) {
    __shared__ bf16 As[2][128 * 32];
    __shared__ bf16 Bs[2][128 * 32];
    const int t = threadIdx.x;
    const int lane = t & 63, wave = t >> 6;
    const int wr = wave >> 1, wc = wave & 1;

    // XCD-chunked bijective swizzle (nwg % 8 == 0 by construction)
    const int nx = gridDim.x, ny = gridDim.y;
    const int lin = blockIdx.y * nx + blockIdx.x;
    const int per = (nx * ny) >> 3;
    const int wg  = (lin & 7) * per + (lin >> 3);
    const int cg  = wg & 7;
    const int t2  = wg >> 3;
    const int by  = t2 % ny, gx = t2 / ny;
    const int m0 = by * 128, n0 = (gx * 8 + cg) * 128;

    const int kz = blockIdx.z;
    const bf16* Az = A  + (size_t)kz * Kslice;
    const bf16* Bz = Bt + (size_t)kz * Kslice;

    f32x4 acc[4][4] = {};

    const int srow = t >> 2;
    const int scol = (t & 3) * 8;
    const bf16* gA = Az + (size_t)(m0 + srow) * Kfull + scol;
    const bf16* gB = Bz + (size_t)(n0 + srow) * Kfull + scol;

    const int fr = lane & 15;
    const int koff = (lane >> 4) * 8;

    // prologue: stage tile 0 into buf 0
    gload_lds16(gA,                        (char*)As[0] + t * 16);
    gload_lds16(gA + (size_t)64 * Kfull,   (char*)As[0] + 4096 + t * 16);
    gload_lds16(gB,                        (char*)Bs[0] + t * 16);
    gload_lds16(gB + (size_t)64 * Kfull,   (char*)Bs[0] + 4096 + t * 16);
    __syncthreads();

    int cur = 0;
    for (int k0 = 32; k0 < Kslice; k0 += 32) {
        gA += 32; gB += 32;
        const int nxt = cur ^ 1;
        gload_lds16(gA,                      (char*)As[nxt] + t * 16);
        gload_lds16(gA + (size_t)64 * Kfull, (char*)As[nxt] + 4096 + t * 16);
        gload_lds16(gB,                      (char*)Bs[nxt] + t * 16);
        gload_lds16(gB + (size_t)64 * Kfull, (char*)Bs[nxt] + 4096 + t * 16);
        GEMM_COMPUTE(cur);
        __syncthreads();   // drains vmcnt(0) (prefetch) + orders buffer reuse
        cur = nxt;
    }
    GEMM_COMPUTE(cur);

    // D layout: col = lane&15, row = (lane>>4)*4 + reg  [m89/m91 verified]
    if (Cf) Cf += (size_t)kz * M * N;
    const int cr = (lane >> 4) * 4;
    const int cc = lane & 15;
#pragma unroll
    for (int i = 0; i < 4; ++i)
#pragma unroll
        for (int j = 0; j < 4; ++j) {
            int col = n0 + wc * 64 + j * 16 + cc;
            float bv = (kz == 0) ? bias[col] : 0.f;
#pragma unroll
            for (int r = 0; r < 4; ++r) {
                int row = m0 + wr * 64 + i * 16 + cr + r;
                float v = acc[i][j][r] + bv;
                if (RELU) v = fmaxf(v, 0.f);
                if (OUT_BF16) Cb[(size_t)row * N + col] = __float2bfloat16(v);
                else          Cf[(size_t)row * N + col] = v;
            }
        }
}

// ---------------------------------------------------------------- MFMA attention
// one block per (b,h). qkvb: bf16 [6400][3072] (Q|K|V, each col = h*64+e).
// Score cols padded to 112 (7 frags), rows/k padded to 128.
// LDS: Ks[112][64] swz, Vt[64][128] swz (V transposed), Ps[128][128] swz.
__global__ __launch_bounds__(256) void attn_mfma_kernel(
    const bf16* __restrict__ qkvb, bf16* __restrict__ ctx) {
    __shared__ bf16 Ks[112 * 64];
    __shared__ bf16 Vt[64 * 128];
    __shared__ bf16 Ps[128 * 128];
    const int b = blockIdx.x >> 4, h = blockIdx.x & 15;
    const int t = threadIdx.x, lane = t & 63, w = t >> 6;
    const int fr = lane & 15, qq = lane >> 4;
    const size_t rbase = (size_t)b * kS * 3072 + (size_t)h * 64;

    for (int i = t; i < 64 * 14; i += 256) {          // Vt k=100..127 := 0
        int e = i / 14, kk = 100 + (i % 14) * 2;
        *(unsigned*)((char*)Vt + e * 256 + ((kk * 2) ^ ((e & 7) << 4))) = 0u;
    }
    for (int i = t; i < 128 * 8; i += 256) {          // Ps cols 112..127 := 0
        int r = i / 8, c = 112 + (i % 8) * 2;
        *(unsigned*)((char*)Ps + r * 256 + ((c * 2) ^ ((r & 7) << 4))) = 0u;
    }
    for (int it = 0; it < 4; ++it) {
        int s = it * 32 + (t >> 3);
        if (s < kS) {
            int e0 = (t & 7) * 8;
            const bf16* kr = qkvb + rbase + (size_t)s * 3072 + 1024 + e0;
            short8 kv = *(const short8*)kr;
            *(short8*)((char*)Ks + s * 128 + ((e0 * 2) ^ ((s & 7) << 4))) = kv;
            short8 vv = *(const short8*)(kr + 1024);
#pragma unroll
            for (int i2 = 0; i2 < 8; ++i2) {
                int e = e0 + i2;
                *(unsigned short*)((char*)Vt + e * 256 + ((s * 2) ^ ((e & 7) << 4))) =
                    ((unsigned short*)&vv)[i2];
            }
        }
    }
    short8 qa[2][2];
#pragma unroll
    for (int rt = 0; rt < 2; ++rt)
#pragma unroll
        for (int ks = 0; ks < 2; ++ks) {
            int q = 32 * w + 16 * rt + fr; q = q < kS ? q : kS - 1;
            qa[rt][ks] = *(const short8*)(qkvb + rbase + (size_t)q * 3072 + 32 * ks + 8 * qq);
        }
    __syncthreads();

    short8 kb[7][2];
#pragma unroll
    for (int j = 0; j < 7; ++j)
#pragma unroll
        for (int ks = 0; ks < 2; ++ks)
            kb[j][ks] = *(const short8*)((char*)Ks + (16 * j + fr) * 128 +
                                         ((64 * ks + 16 * qq) ^ ((fr & 7) << 4)));

    f32x4 sc[2][7] = {};
#pragma unroll
    for (int rt = 0; rt < 2; ++rt)
#pragma unroll
        for (int j = 0; j < 7; ++j)
#pragma unroll
            for (int ks = 0; ks < 2; ++ks)
                sc[rt][j] = __builtin_amdgcn_mfma_f32_16x16x32_bf16(
                    qa[rt][ks], kb[j][ks], sc[rt][j], 0, 0, 0);

    float inv_l[2][4];
#pragma unroll
    for (int rt = 0; rt < 2; ++rt)
#pragma unroll
        for (int r = 0; r < 4; ++r) {
            float v[7];
#pragma unroll
            for (int j = 0; j < 7; ++j) v[j] = sc[rt][j][r] * 0.125f;
            if (fr >= 4) v[6] = -INFINITY;
            float m = v[0];
#pragma unroll
            for (int j = 1; j < 7; ++j) m = fmaxf(m, v[j]);
#pragma unroll
            for (int off = 8; off; off >>= 1) m = fmaxf(m, __shfl_xor(m, off));
            int row = 32 * w + 16 * rt + qq * 4 + r;
            float s = 0.f;
#pragma unroll
            for (int j = 0; j < 7; ++j) {
                float p = __expf(v[j] - m);
                s += p;
                *(bf16*)((char*)Ps + row * 256 + (((16 * j + fr) * 2) ^ ((row & 7) << 4))) =
                    __float2bfloat16(p);
            }
#pragma unroll
            for (int off = 8; off; off >>= 1) s += __shfl_xor(s, off);
            inv_l[rt][r] = 1.f / s;
        }
    __syncthreads();

    short8 pa[2][4];
#pragma unroll
    for (int rt = 0; rt < 2; ++rt)
#pragma unroll
        for (int ks = 0; ks < 4; ++ks) {
            int row = 32 * w + 16 * rt + fr;
            pa[rt][ks] = *(const short8*)((char*)Ps + row * 256 +
                                          ((64 * ks + 16 * qq) ^ ((fr & 7) << 4)));
        }
#pragma unroll
    for (int e = 0; e < 4; ++e) {
        short8 vb[4];
#pragma unroll
        for (int ks = 0; ks < 4; ++ks)
            vb[ks] = *(const short8*)((char*)Vt + (16 * e + fr) * 256 +
                                      ((64 * ks + 16 * qq) ^ ((fr & 7) << 4)));
#pragma unroll
        for (int rt = 0; rt < 2; ++rt) {
            f32x4 o = {};
#pragma unroll
            for (int ks = 0; ks < 4; ++ks)
                o = __builtin_amdgcn_mfma_f32_16x16x32_bf16(pa[rt][ks], vb[ks], o, 0, 0, 0);
#pragma unroll
            for (int r = 0; r < 4; ++r) {
                int q = 32 * w + 16 * rt + qq * 4 + r;
                if (q < kS)
                    ctx[((size_t)b * kS + q) * kD + h * 64 + 16 * e + fr] =
                        __float2bfloat16(o[r] * inv_l[rt][r]);
            }
        }
    }
}

// ---------------------------------------------------------------- add(+add2) + LN
__global__ __launch_bounds__(256) void add_ln_kernel(
    const float* __restrict__ a, const float* __restrict__ a2,
    const float* __restrict__ r,
    const float* __restrict__ gamma, const float* __restrict__ beta,
    float* __restrict__ outf, bf16* __restrict__ outb) {
    __shared__ float red[10];
    int row = blockIdx.x, t = threadIdx.x, lane = t & 63, w = t >> 6;
    const float4 va = ((const float4*)(a + (size_t)row * kD))[t];
    const float4 vr = ((const float4*)(r + (size_t)row * kD))[t];
    float4 x; x.x = va.x + vr.x; x.y = va.y + vr.y; x.z = va.z + vr.z; x.w = va.w + vr.w;
    if (a2) {
        const float4 v2 = ((const float4*)(a2 + (size_t)row * kD))[t];
        x.x += v2.x; x.y += v2.y; x.z += v2.z; x.w += v2.w;
    }
    float s  = x.x + x.y + x.z + x.w;
    float ss = x.x * x.x + x.y * x.y + x.z * x.z + x.w * x.w;
#pragma unroll
    for (int off = 32; off; off >>= 1) {
        s += __shfl_xor(s, off); ss += __shfl_xor(ss, off);
    }
    if (lane == 0) { red[w] = s; red[4 + w] = ss; }
    __syncthreads();
    if (t == 0) {
        float S = red[0] + red[1] + red[2] + red[3];
        float Q = red[4] + red[5] + red[6] + red[7];
        float mean = S / kD;
        float var  = Q / kD - mean * mean;
        red[8] = mean; red[9] = rsqrtf(var + 1e-6f);
    }
    __syncthreads();
    float mean = red[8], rstd = red[9];
    const float4 g  = ((const float4*)gamma)[t];
    const float4 be = ((const float4*)beta)[t];
    float4 o;
    o.x = g.x * ((x.x - mean) * rstd) + be.x;
    o.y = g.y * ((x.y - mean) * rstd) + be.y;
    o.z = g.z * ((x.z - mean) * rstd) + be.z;
    o.w = g.w * ((x.w - mean) * rstd) + be.w;
    ((float4*)(outf + (size_t)row * kD))[t] = o;
    if (outb) {
        BF4 p; p.b[0] = __float2bfloat16(o.x); p.b[1] = __float2bfloat16(o.y);
        p.b[2] = __float2bfloat16(o.z); p.b[3] = __float2bfloat16(o.w);
        *(uint2*)(outb + (size_t)row * kD + t * 4) = p.u;
    }
}

// ---------------------------------------------------------------- launcher
// Workspace (peak 169,766,912 B, proven ws fits >182 MB):
//  xf      @0            26,214,400  [embed -> LN1]
//  xb/ctx  @26,214,400   13,107,200  [embed->QKV; attn->Wo]
//  qkvb    @39,321,600   39,321,600  [QKV -> attn]
//  hbuf    @0            52,428,800  [FFN1 -> FFN2] (aliases xf+xb+qkvb head, dead)
//  ffp     @52,428,800   52,428,800  [FFN2 partials z0,z1 -> LN2] (qkvb tail+attout dead)
//  attout  @78,643,200   26,214,400  [Wo -> LN1] (overwritten by ffp z1 after LN1)
//  x1f     @104,857,600  26,214,400  [LN1 -> LN2]
//  x1b     @131,072,000  13,107,200  [LN1 -> FFN1]
//  pe/weights/bias @144,179,200 .. 169,766,912 (resident)
extern "C" void kernel_launch(void* const* d_in, const int* in_sizes, int n_in,
                              void* d_out, int out_size, void* d_ws, size_t ws_size,
                              hipStream_t stream) {
    const int*   tokens = (const int*)d_in[0];
    const float* emb    = (const float*)d_in[1];
    const float* Wq     = (const float*)d_in[2];
    const float* bq     = (const float*)d_in[3];
    const float* Wk     = (const float*)d_in[4];
    const float* bk     = (const float*)d_in[5];
    const float* Wv     = (const float*)d_in[6];
    const float* bv     = (const float*)d_in[7];
    const float* Wo     = (const float*)d_in[8];
    const float* bo     = (const float*)d_in[9];
    const float* W1     = (const float*)d_in[10];
    const float* b1     = (const float*)d_in[11];
    const float* W2     = (const float*)d_in[12];
    const float* b2     = (const float*)d_in[13];
    const float* g1     = (const float*)d_in[14];
    const float* be1    = (const float*)d_in[15];
    const float* g2     = (const float*)d_in[16];
    const float* be2    = (const float*)d_in[17];

    char* ws = (char*)d_ws;
    float* xf     = (float*)(ws + 0);
    bf16*  xb     = (bf16*) (ws + 26214400);
    bf16*  qkvb   = (bf16*) (ws + 39321600);
    bf16*  hbuf   = (bf16*) (ws + 0);
    float* ffp    = (float*)(ws + 52428800);     // 2 partials, 26.2 MB each
    float* attout = (float*)(ws + 78643200);
    float* x1f    = (float*)(ws + 104857600);
    bf16*  x1b    = (bf16*) (ws + 131072000);
    float* pe     = (float*)(ws + 144179200);
    bf16*  wqkvt  = (bf16*) (ws + 144588800);
    bf16*  wot    = (bf16*) (ws + 150880256);
    bf16*  w1t    = (bf16*) (ws + 152977408);
    bf16*  w2t    = (bf16*) (ws + 161366016);
    float* bqkv   = (float*)(ws + 169754624);

    prep_kernel<<<3484, 256, 0, stream>>>(Wq, Wk, Wv, Wo, W1, W2, bq, bk, bv,
                                          wqkvt, wot, w1t, w2t, bqkv, pe);
    embed_kernel<<<kRows, 256, 0, stream>>>(tokens, emb, pe, xf, xb);

    // QKV: [6400,3072] -> bf16
    gemm_kernel<false, true><<<dim3(24, 50, 1), 256, 0, stream>>>(
        xb, wqkvt, bqkv, nullptr, qkvb, kRows, 3072, 1024, 1024);
    // attention -> ctx (bf16, concat-head layout) into xb
    attn_mfma_kernel<<<kB * kH, 256, 0, stream>>>(qkvb, xb);
    // Wo: [6400,1024]
    gemm_kernel<false, false><<<dim3(8, 50, 1), 256, 0, stream>>>(
        xb, wot, bo, attout, nullptr, kRows, 1024, 1024, 1024);
    add_ln_kernel<<<kRows, 256, 0, stream>>>(attout, nullptr, xf, g1, be1, x1f, x1b);
    // FFN1: [6400,4096] + bias + ReLU -> bf16
    gemm_kernel<true, true><<<dim3(32, 50, 1), 256, 0, stream>>>(
        x1b, w1t, b1, nullptr, hbuf, kRows, 4096, 1024, 1024);
    // FFN2: [6400,1024], split-K=2 via grid.z -> two f32 partials
    gemm_kernel<false, false><<<dim3(8, 50, 2), 256, 0, stream>>>(
        hbuf, w2t, b2, ffp, nullptr, kRows, 1024, 4096, 2048);
    add_ln_kernel<<<kRows, 256, 0, stream>>>(ffp, ffp + (size_t)kRows * kD, x1f,
                                             g2, be2, (float*)d_out, nullptr);
}